// Round 1
// baseline (89.805 us; speedup 1.0000x reference)
//
#include <hip/hip_runtime.h>

// LaughingHyenaModalFilter: h[t,d] = Re(sum_k R[k,d] * p[k,d]^t), p = r e^{i theta}
// out (D, L): out[d, 0] = h_0[d]; out[d, l] = sum_k r^t (Rre cos(t th) - Rim sin(t th)), t = l-1.
// K=32, D=1024, L=2048 fixed by setup_inputs.

#define KP 32
#define DD 1024
#define LL 2048

__global__ __launch_bounds__(256) void modal_filter_kernel(
    const float* __restrict__ r, const float* __restrict__ theta,
    const float* __restrict__ Rre, const float* __restrict__ Rim,
    const float* __restrict__ h0, float* __restrict__ out) {
  const int d = blockIdx.x;     // one block per channel d
  const int tid = threadIdx.x;  // 256 threads cover l = tid, tid+256, ...

  // Stage the 32 poles' params for this d in LDS (read once from global).
  __shared__ float s_lr[KP];   // ln(r)
  __shared__ float s_th[KP];   // theta
  __shared__ float s_Rre[KP];
  __shared__ float s_Rim[KP];
  if (tid < KP) {
    s_lr[tid]  = __logf(r[tid * DD + d]);
    s_th[tid]  = theta[tid * DD + d];
    s_Rre[tid] = Rre[tid * DD + d];
    s_Rim[tid] = Rim[tid * DD + d];
  }
  __syncthreads();

  float* outd = out + (size_t)d * LL;

  for (int l = tid; l < LL; l += 256) {
    float acc;
    if (l == 0) {
      acc = h0[d];
    } else {
      const float t = (float)(l - 1);
      acc = 0.0f;
#pragma unroll
      for (int k = 0; k < KP; ++k) {
        const float mag = __expf(t * s_lr[k]);   // r^t
        float s, c;
        __sincosf(t * s_th[k], &s, &c);
        // acc += mag * (Rre*c - Rim*s)
        acc = fmaf(mag, fmaf(s_Rre[k], c, -(s_Rim[k] * s)), acc);
      }
    }
    outd[l] = acc;  // coalesced: consecutive tid -> consecutive l
  }
}

extern "C" void kernel_launch(void* const* d_in, const int* in_sizes, int n_in,
                              void* d_out, int out_size, void* d_ws, size_t ws_size,
                              hipStream_t stream) {
  const float* r     = (const float*)d_in[0];
  const float* theta = (const float*)d_in[1];
  const float* Rre   = (const float*)d_in[2];
  const float* Rim   = (const float*)d_in[3];
  const float* h0    = (const float*)d_in[4];
  float* out = (float*)d_out;

  modal_filter_kernel<<<DD, 256, 0, stream>>>(r, theta, Rre, Rim, h0, out);
}

// Round 2
// 80.044 us; speedup vs baseline: 1.1219x; 1.1219x over previous
//
#include <hip/hip_runtime.h>

// LaughingHyenaModalFilter: out[d,0]=h0[d]; out[d,l]=Re(sum_k R[k,d]*p[k,d]^(l-1)), p=r e^{i theta}.
// K=32, D=1024, L=2048.
//
// Strategy: one block per d, 256 threads. Thread j owns l in {j, j+256, ..., j+1792}
// (coalesced stores). Complex recurrence: z_k init at t0=j-1 via native exp2/sin/cos
// (hardware v_sin_f32 takes REVOLUTIONS -> pre-scale theta by 1/2pi, v_fract first),
// then z_k *= q_k with q_k = p_k^256 precomputed per block in LDS.

#define KP 32
#define DD 1024
#define LL 2048
#define INV_2PI 0x1.45f306p-3f  // 1/(2*pi)

__global__ __launch_bounds__(256) void modal_filter_kernel(
    const float* __restrict__ r, const float* __restrict__ theta,
    const float* __restrict__ Rre, const float* __restrict__ Rim,
    const float* __restrict__ h0, float* __restrict__ out) {
  const int d = blockIdx.x;
  const int tid = threadIdx.x;

  __shared__ float s_lr[KP];   // log2(r)
  __shared__ float s_thr[KP];  // theta / (2*pi)  (revolutions)
  __shared__ float s_qre[KP];  // Re(p^256)
  __shared__ float s_qim[KP];  // Im(p^256)
  __shared__ float s_Rre[KP];
  __shared__ float s_Rim[KP];

  if (tid < KP) {
    const float rv = r[tid * DD + d];
    const float th = theta[tid * DD + d];
    const float lr = __builtin_amdgcn_logf(rv);   // v_log_f32: log2
    const float thr = th * INV_2PI;
    const float qmag = __builtin_amdgcn_exp2f(256.0f * lr);          // r^256
    const float qang = __builtin_amdgcn_fractf(256.0f * thr);
    s_lr[tid] = lr;
    s_thr[tid] = thr;
    s_qre[tid] = qmag * __builtin_amdgcn_cosf(qang);
    s_qim[tid] = qmag * __builtin_amdgcn_sinf(qang);
    s_Rre[tid] = Rre[tid * DD + d];
    s_Rim[tid] = Rim[tid * DD + d];
  }
  __syncthreads();

  // Init z_k = R_k * p_k^{t0}, t0 = tid-1 (tid 0 inits at t=-1; its l=0 slot is h0).
  float zre[KP], zim[KP], qre[KP], qim[KP];
  const float t0 = (float)tid - 1.0f;
#pragma unroll
  for (int k = 0; k < KP; ++k) {
    const float mag = __builtin_amdgcn_exp2f(t0 * s_lr[k]);   // r^t0
    const float ang = __builtin_amdgcn_fractf(t0 * s_thr[k]);
    const float c = __builtin_amdgcn_cosf(ang);               // cos(2*pi*ang)
    const float s = __builtin_amdgcn_sinf(ang);
    const float wre = mag * c, wim = mag * s;                 // p^t0
    zre[k] = s_Rre[k] * wre - s_Rim[k] * wim;
    zim[k] = s_Rre[k] * wim + s_Rim[k] * wre;
    qre[k] = s_qre[k];
    qim[k] = s_qim[k];
  }

  float* outd = out + (size_t)d * LL;
  const float h0d = h0[d];

#pragma unroll
  for (int s = 0; s < 8; ++s) {
    // h[t] contribution: sum of real parts (4-way split to shorten the add chain)
    float a0 = 0.f, a1 = 0.f, a2 = 0.f, a3 = 0.f;
#pragma unroll
    for (int k = 0; k < KP; k += 4) {
      a0 += zre[k];
      a1 += zre[k + 1];
      a2 += zre[k + 2];
      a3 += zre[k + 3];
    }
    const float acc = (a0 + a1) + (a2 + a3);
    const int l = tid + 256 * s;
    outd[l] = (l == 0) ? h0d : acc;  // coalesced across the wave
    if (s < 7) {
#pragma unroll
      for (int k = 0; k < KP; ++k) {
        const float nr = zre[k] * qre[k] - zim[k] * qim[k];
        const float ni = zre[k] * qim[k] + zim[k] * qre[k];
        zre[k] = nr;
        zim[k] = ni;
      }
    }
  }
}

extern "C" void kernel_launch(void* const* d_in, const int* in_sizes, int n_in,
                              void* d_out, int out_size, void* d_ws, size_t ws_size,
                              hipStream_t stream) {
  const float* r     = (const float*)d_in[0];
  const float* theta = (const float*)d_in[1];
  const float* Rre   = (const float*)d_in[2];
  const float* Rim   = (const float*)d_in[3];
  const float* h0    = (const float*)d_in[4];
  float* out = (float*)d_out;

  modal_filter_kernel<<<DD, 256, 0, stream>>>(r, theta, Rre, Rim, h0, out);
}

// Round 3
// 73.489 us; speedup vs baseline: 1.2220x; 1.0892x over previous
//
#include <hip/hip_runtime.h>

// LaughingHyenaModalFilter: out[d,0]=h0[d]; out[d,l]=Re(sum_k R[k,d]*p[k,d]^(l-1)), p=r e^{i theta}.
// K=32, D=1024, L=2048.
//
// One block per d, 256 threads; thread j owns l in {j, j+256, ...} (coalesced stores).
// Complex recurrence z_k *= q_k (q_k = p_k^256, per-block in LDS), init via native
// exp2/fract/sin/cos (v_sin_f32 takes REVOLUTIONS -> theta pre-scaled by 1/2pi).
// k-pairs packed into float2 so the main loop lowers to v_pk_fma_f32/v_pk_mul_f32
// (dual-FP32 VOP3P, 2x scalar FP32 rate) -> ~halves main-loop instruction count.

#define KP 32
#define KP2 16
#define DD 1024
#define LL 2048
#define INV_2PI 0x1.45f306p-3f  // 1/(2*pi)

typedef float v2f __attribute__((ext_vector_type(2)));

__global__ __launch_bounds__(256) void modal_filter_kernel(
    const float* __restrict__ r, const float* __restrict__ theta,
    const float* __restrict__ Rre, const float* __restrict__ Rim,
    const float* __restrict__ h0, float* __restrict__ out) {
  const int d = blockIdx.x;
  const int tid = threadIdx.x;

  __shared__ float s_lr[KP];   // log2(r)
  __shared__ float s_thr[KP];  // theta / (2*pi)
  __shared__ float s_qre[KP];  // Re(p^256)
  __shared__ float s_qim[KP];  // Im(p^256)
  __shared__ float s_Rre[KP];
  __shared__ float s_Rim[KP];

  if (tid < KP) {
    const float rv = r[tid * DD + d];
    const float th = theta[tid * DD + d];
    const float lr = __builtin_amdgcn_logf(rv);   // v_log_f32: log2
    const float thr = th * INV_2PI;
    const float qmag = __builtin_amdgcn_exp2f(256.0f * lr);   // r^256
    const float qang = __builtin_amdgcn_fractf(256.0f * thr);
    s_lr[tid] = lr;
    s_thr[tid] = thr;
    s_qre[tid] = qmag * __builtin_amdgcn_cosf(qang);
    s_qim[tid] = qmag * __builtin_amdgcn_sinf(qang);
    s_Rre[tid] = Rre[tid * DD + d];
    s_Rim[tid] = Rim[tid * DD + d];
  }
  __syncthreads();

  // z_k = R_k * p_k^{t0}, t0 = tid-1 (tid 0's l=0 slot is h0). Packed 2 k's per reg.
  v2f ZRE[KP2], ZIM[KP2], QRE[KP2], QIM[KP2];
  const float t0 = (float)tid - 1.0f;
#pragma unroll
  for (int kk = 0; kk < KP2; ++kk) {
#pragma unroll
    for (int j = 0; j < 2; ++j) {
      const int k = 2 * kk + j;
      const float mag = __builtin_amdgcn_exp2f(t0 * s_lr[k]);   // r^t0
      const float ang = __builtin_amdgcn_fractf(t0 * s_thr[k]);
      const float c = __builtin_amdgcn_cosf(ang);               // cos(2*pi*ang)
      const float s = __builtin_amdgcn_sinf(ang);
      const float wre = mag * c, wim = mag * s;                 // p^t0
      ZRE[kk][j] = s_Rre[k] * wre - s_Rim[k] * wim;
      ZIM[kk][j] = s_Rre[k] * wim + s_Rim[k] * wre;
      QRE[kk][j] = s_qre[k];
      QIM[kk][j] = s_qim[k];
    }
  }

  float* outd = out + (size_t)d * LL;
  const float h0d = h0[d];

#pragma unroll
  for (int s = 0; s < 8; ++s) {
    // h contribution = sum_k Re(z_k); 4 packed accumulators to shorten dep chains.
    v2f a0 = {0.f, 0.f}, a1 = {0.f, 0.f}, a2 = {0.f, 0.f}, a3 = {0.f, 0.f};
#pragma unroll
    for (int kk = 0; kk < KP2; kk += 4) {
      a0 += ZRE[kk];
      a1 += ZRE[kk + 1];
      a2 += ZRE[kk + 2];
      a3 += ZRE[kk + 3];
    }
    const v2f aa = (a0 + a1) + (a2 + a3);
    const float acc = aa[0] + aa[1];
    const int l = tid + 256 * s;
    outd[l] = (l == 0) ? h0d : acc;  // coalesced across the wave
    if (s < 7) {
#pragma unroll
      for (int kk = 0; kk < KP2; ++kk) {
        const v2f nr = ZRE[kk] * QRE[kk] - ZIM[kk] * QIM[kk];  // v_pk_mul + v_pk_fma
        const v2f ni = ZRE[kk] * QIM[kk] + ZIM[kk] * QRE[kk];
        ZRE[kk] = nr;
        ZIM[kk] = ni;
      }
    }
  }
}

extern "C" void kernel_launch(void* const* d_in, const int* in_sizes, int n_in,
                              void* d_out, int out_size, void* d_ws, size_t ws_size,
                              hipStream_t stream) {
  const float* r     = (const float*)d_in[0];
  const float* theta = (const float*)d_in[1];
  const float* Rre   = (const float*)d_in[2];
  const float* Rim   = (const float*)d_in[3];
  const float* h0    = (const float*)d_in[4];
  float* out = (float*)d_out;

  modal_filter_kernel<<<DD, 256, 0, stream>>>(r, theta, Rre, Rim, h0, out);
}